// Round 4
// baseline (627.266 us; speedup 1.0000x reference)
//
#include <hip/hip_runtime.h>
#include <hip/hip_bf16.h>
#include <math.h>

typedef short short8 __attribute__((ext_vector_type(8)));
typedef float floatx4 __attribute__((ext_vector_type(4)));

#define NBLK 512

__device__ __forceinline__ ushort f2bf(float f) {
    __hip_bfloat16 h = __float2bfloat16(f);
    return *reinterpret_cast<ushort*>(&h);
}
__device__ __forceinline__ void bf8_to_f32(uint4 u, float* f) {
    f[0] = __uint_as_float(u.x << 16); f[1] = __uint_as_float(u.x & 0xffff0000u);
    f[2] = __uint_as_float(u.y << 16); f[3] = __uint_as_float(u.y & 0xffff0000u);
    f[4] = __uint_as_float(u.z << 16); f[5] = __uint_as_float(u.z & 0xffff0000u);
    f[6] = __uint_as_float(u.w << 16); f[7] = __uint_as_float(u.w & 0xffff0000u);
}

#define GLDS16(g, l) __builtin_amdgcn_global_load_lds( \
    (const __attribute__((address_space(1))) void*)(g), \
    (__attribute__((address_space(3))) void*)(l), 16, 0, 0)

// Monotonic grid barrier. All 512 blocks are co-resident by construction
// (launch_bounds(256,2) -> 2 blocks/CU x 256 CU; LDS 43520 -> 3/CU fits).
// Device-scope release (threadfence) before add, acquire after spin (G16).
__device__ __forceinline__ void gbar(uint* cnt, uint target) {
    __syncthreads();
    __threadfence();
    if (threadIdx.x == 0) {
        __hip_atomic_fetch_add(cnt, 1u, __ATOMIC_ACQ_REL, __HIP_MEMORY_SCOPE_AGENT);
        uint v;
        do {
            __builtin_amdgcn_s_sleep(1);
            v = __hip_atomic_load(cnt, __ATOMIC_ACQUIRE, __HIP_MEMORY_SCOPE_AGENT);
        } while (v < target);
    }
    __syncthreads();
    __threadfence();
}

struct FusedArgs {
    const float *W1, *W2, *Wq, *Wk, *Wv, *Wo, *bq, *bv, *bo, *b1, *b2;
    const float *query, *qpos;
    ushort *W1t, *W2t, *Wqkvt, *Wot, *queryB, *embB;
    float *biasC;
    ushort *hiddenB, *peB, *qkvB, *xB;
    float *out;
    uint *bars;
};

// ---------------------------------------------------------------------------
// P0 task helpers (prep: weight transposes, query cast, emb featurize)
__device__ void transpose_task(int t, const FusedArgs& a, char* smem) {
    const float* src; ushort* dst; int R, z, by, bx;
    if (t < 128) { z = 0; by = t >> 4; bx = t & 15; }
    else { int u = t - 128; z = 1 + (u >> 8); int idx = u & 255; by = idx >> 4; bx = idx & 15; }
    switch (z) {
        case 0:  src = a.W1; dst = a.W1t;                R = 256; break;
        case 1:  src = a.W2; dst = a.W2t;                R = 512; break;
        case 2:  src = a.Wq; dst = a.Wqkvt;              R = 512; break;
        case 3:  src = a.Wk; dst = a.Wqkvt + 512 * 512;  R = 512; break;
        case 4:  src = a.Wv; dst = a.Wqkvt + 1024 * 512; R = 512; break;
        default: src = a.Wo; dst = a.Wot;                R = 512; break;
    }
    const int r0 = by * 32, c0 = bx * 32;
    const int tid = threadIdx.x;
    const int tx = tid & 31, ty = tid >> 5;
    float* tt = (float*)smem;   // [32][33]
    __syncthreads();            // LDS reuse guard
    for (int i = ty; i < 32; i += 8) tt[i * 33 + tx] = src[(size_t)(r0 + i) * 512 + c0 + tx];
    __syncthreads();
    for (int i = ty; i < 32; i += 8) dst[(size_t)(c0 + i) * R + r0 + tx] = f2bf(tt[tx * 33 + i]);
}

__device__ void qcast_task(int bid, const FusedArgs& a) {
    const int tid = threadIdx.x;
#pragma unroll
    for (int i = 0; i < 8; ++i) {
        size_t idx4 = (size_t)bid * 2048 + i * 256 + tid;
        float4 v = *(const float4*)(a.query + idx4 * 4);
        ushort4 o; o.x = f2bf(v.x); o.y = f2bf(v.y); o.z = f2bf(v.z); o.w = f2bf(v.w);
        *(ushort4*)(a.queryB + idx4 * 4) = o;
    }
    if (bid == 0) {
        for (int i = tid; i < 1536; i += 256)
            a.biasC[i] = (i < 512) ? a.bq[i] : ((i < 1024) ? 0.0f : a.bv[i - 1024]);
    }
}

__device__ void emb_task(int bid, const FusedArgs& a) {
    const int tid = threadIdx.x;
    const int gt = bid * 256 + tid;
    const int e0 = gt * 16;
    const int r = e0 >> 8, j0 = e0 & 255;
    const float t = a.qpos[r];
    ushort o[16];
#pragma unroll
    for (int u = 0; u < 16; ++u) {
        int j = j0 + u, i = j & 127;
        float freq = __expf(-9.210340371976184f * (float)i * (1.0f / 128.0f));
        float ang = t * freq;
        o[u] = f2bf((j < 128) ? __cosf(ang) : __sinf(ang));
    }
    *(uint4*)(a.embB + e0)     = *(uint4*)&o[0];
    *(uint4*)(a.embB + e0 + 8) = *(uint4*)&o[8];
}

// ---------------------------------------------------------------------------
// One BM x BN GEMM tile, dbuf LDS pipeline, global_load_lds width=16, 4 waves.
template<int BM, int BN>
__device__ void gemm_tile(const ushort* __restrict__ A, const ushort* __restrict__ Bt,
                          const float* __restrict__ bias, const float* __restrict__ resid,
                          void* __restrict__ Cout, int N, int K, int act, int outf32,
                          int ntn, int bid, char* smem) {
    constexpr int MR = BM / 32;
    constexpr int NR = BN / 32;
    ushort* As = (ushort*)smem;           // 2 x BM*32
    ushort* Bs = As + 2 * BM * 32;        // 2 x BN*32
    const int tm = bid / ntn, tn = bid % ntn;
    const int row0 = tm * BM, col0 = tn * BN;

    const int tid = threadIdx.x;
    const int l = tid & 63, w = tid >> 6;
    const int wr = w >> 1, wc = w & 1;
    const int l15 = l & 15, quad = l >> 4;

    const int srow = tid >> 2;
    const int skoff = (tid & 3) * 8;
    const ushort* gA = A  + (size_t)(row0 + srow) * K + skoff;
    const ushort* gB = Bt + (size_t)(col0 + srow) * K + skoff;

    auto stage = [&](int s, int k0) {
#pragma unroll
        for (int i = 0; i < BM / 64; ++i)
            GLDS16(gA + (size_t)(i * 64) * K + k0, &As[(size_t)s * BM * 32 + (i * 256 + tid) * 8]);
#pragma unroll
        for (int i = 0; i < BN / 64; ++i)
            GLDS16(gB + (size_t)(i * 64) * K + k0, &Bs[(size_t)s * BN * 32 + (i * 256 + tid) * 8]);
    };

    floatx4 acc[MR][NR] = {};
    const int nk = K >> 5;
    __syncthreads();            // LDS reuse guard vs previous phase/call
    stage(0, 0);
    int cur = 0;
    for (int t = 0; t < nk; ++t) {
        __syncthreads();        // drains vmcnt(0): stage(t) visible
        if (t + 1 < nk) stage(cur ^ 1, (t + 1) * 32);   // prefetch early
        const ushort* Ab = As + (size_t)cur * BM * 32;
        const ushort* Bb = Bs + (size_t)cur * BN * 32;
        short8 af[MR], bf[NR];
#pragma unroll
        for (int m = 0; m < MR; ++m)
            af[m] = *(const short8*)&Ab[(wr * (BM / 2) + m * 16 + l15) * 32 + quad * 8];
#pragma unroll
        for (int n = 0; n < NR; ++n)
            bf[n] = *(const short8*)&Bb[(wc * (BN / 2) + n * 16 + l15) * 32 + quad * 8];
#pragma unroll
        for (int m = 0; m < MR; ++m)
#pragma unroll
            for (int n = 0; n < NR; ++n)
                acc[m][n] = __builtin_amdgcn_mfma_f32_16x16x32_bf16(af[m], bf[n], acc[m][n], 0, 0, 0);
        cur ^= 1;
    }

#pragma unroll
    for (int m = 0; m < MR; ++m)
#pragma unroll
        for (int n = 0; n < NR; ++n) {
            int col = col0 + wc * (BN / 2) + n * 16 + l15;
            float bvv = bias ? bias[col] : 0.0f;
#pragma unroll
            for (int r = 0; r < 4; ++r) {
                int row = row0 + wr * (BM / 2) + m * 16 + quad * 4 + r;
                float val = acc[m][n][r] + bvv;
                if (act) val = val / (1.0f + __expf(-val));
                if (outf32) {
                    float rv = resid ? resid[(size_t)row * N + col] : 0.0f;
                    ((float*)Cout)[(size_t)row * N + col] = val + rv;
                } else {
                    ((ushort*)Cout)[(size_t)row * N + col] = f2bf(val);
                }
            }
        }
}

// ---------------------------------------------------------------------------
// One attention unit (h, b, nh): 32 q-rows vs 64 keys, head dim 64.
// LDS rows padded to 68 floats: stride mod 32 banks = 4 -> the wave's float4
// reads spread over all 8 span positions (conflict-free-optimal for b128).
// pe loads for all 8 m-groups batched before the compute loop.
__device__ void attn_unit(const ushort* __restrict__ qkv, const ushort* __restrict__ peB,
                          ushort* __restrict__ xB, int h, int b, int nh, char* smem) {
    constexpr int LP = 68;
    float* ks = (float*)smem;       // [64][68]
    float* vs = ks + 64 * LP;       // [64][68]
    float* qs = vs + 64 * LP;       // [32][68]
    const int tid = threadIdx.x;
    const int w = tid >> 6, l = tid & 63;
    const int lo = l & 7, hi = l >> 3;

    __syncthreads();                // LDS reuse guard
#pragma unroll
    for (int p = 0; p < 2; ++p) {
        int cid = p * 256 + tid;
        int row = cid >> 3, ch = cid & 7;
        const ushort* base = qkv + (size_t)(b * 64 + row) * 1536 + h * 64 + ch * 8;
        uint4 ku = *(const uint4*)(base + 512);
        uint4 vu = *(const uint4*)(base + 1024);
        float kf[8], vf[8];
        bf8_to_f32(ku, kf); bf8_to_f32(vu, vf);
#pragma unroll
        for (int j = 0; j < 8; ++j) {
            ks[row * LP + ch * 8 + j] = kf[j];
            vs[row * LP + ch * 8 + j] = vf[j];
        }
    }
    {
        int row = tid >> 3, ch = tid & 7;
        uint4 qu = *(const uint4*)(qkv + (size_t)(b * 64 + nh * 32 + row) * 1536 + h * 64 + ch * 8);
        float qf[8]; bf8_to_f32(qu, qf);
#pragma unroll
        for (int j = 0; j < 8; ++j) qs[row * LP + ch * 8 + j] = qf[j];
    }
    __syncthreads();

    for (int i = 0; i < 8; ++i) {
        int nl = w + 4 * i;
        int n = nh * 32 + nl;
        float qf[8];
        *(float4*)&qf[0] = *(const float4*)&qs[nl * LP + lo * 8];
        *(float4*)&qf[4] = *(const float4*)&qs[nl * LP + lo * 8 + 4];

        uint4 pu[8];
#pragma unroll
        for (int mg = 0; mg < 8; ++mg)
            pu[mg] = *(const uint4*)(peB + (size_t)(n * 64 + mg * 8 + hi) * 512 + h * 64 + lo * 8);

        float sreg[8];
#pragma unroll
        for (int mg = 0; mg < 8; ++mg) {
            int m = mg * 8 + hi;
            float pf[8]; bf8_to_f32(pu[mg], pf);
            float kf[8];
            *(float4*)&kf[0] = *(const float4*)&ks[m * LP + lo * 8];
            *(float4*)&kf[4] = *(const float4*)&ks[m * LP + lo * 8 + 4];
            float p = 0.0f;
#pragma unroll
            for (int j = 0; j < 8; ++j) p = fmaf(qf[j] * kf[j], pf[j], p);
            p += __shfl_xor(p, 1);
            p += __shfl_xor(p, 2);
            p += __shfl_xor(p, 4);
            sreg[mg] = p * 0.125f;
        }

        float mx = sreg[0];
#pragma unroll
        for (int mg = 1; mg < 8; ++mg) mx = fmaxf(mx, sreg[mg]);
        mx = fmaxf(mx, __shfl_xor(mx, 8));
        mx = fmaxf(mx, __shfl_xor(mx, 16));
        mx = fmaxf(mx, __shfl_xor(mx, 32));
        float sum = 0.0f;
#pragma unroll
        for (int mg = 0; mg < 8; ++mg) { sreg[mg] = __expf(sreg[mg] - mx); sum += sreg[mg]; }
        sum += __shfl_xor(sum, 8);
        sum += __shfl_xor(sum, 16);
        sum += __shfl_xor(sum, 32);
        float rs = 1.0f / sum;

        float acc[8] = {};
#pragma unroll
        for (int mg = 0; mg < 8; ++mg) {
            int m = mg * 8 + hi;
            float at = sreg[mg] * rs;
            float vf[8];
            *(float4*)&vf[0] = *(const float4*)&vs[m * LP + lo * 8];
            *(float4*)&vf[4] = *(const float4*)&vs[m * LP + lo * 8 + 4];
#pragma unroll
            for (int j = 0; j < 8; ++j) acc[j] = fmaf(at, vf[j], acc[j]);
        }
#pragma unroll
        for (int j = 0; j < 8; ++j) {
            acc[j] += __shfl_xor(acc[j], 8);
            acc[j] += __shfl_xor(acc[j], 16);
            acc[j] += __shfl_xor(acc[j], 32);
        }
        if (l < 8) {
            uint4 o;
            o.x = f2bf(acc[0]) | ((uint)f2bf(acc[1]) << 16);
            o.y = f2bf(acc[2]) | ((uint)f2bf(acc[3]) << 16);
            o.z = f2bf(acc[4]) | ((uint)f2bf(acc[5]) << 16);
            o.w = f2bf(acc[6]) | ((uint)f2bf(acc[7]) << 16);
            *(uint4*)(xB + (size_t)(b * 64 + n) * 512 + h * 64 + l * 8) = o;
        }
    }
}

// ---------------------------------------------------------------------------
// The whole network in one launch. 512 blocks x 256 threads, all co-resident
// (2 blocks/CU); manual grid barriers between phases.
__global__ __launch_bounds__(256, 2) void fused_all(FusedArgs a) {
    __shared__ __align__(16) char smem[43520];
    const int blk = blockIdx.x;

    // P0: prep (1408 transpose tiles + 256 qcast + 256 emb = 1920 tasks)
    for (int task = blk; task < 1920; task += NBLK) {
        if (task < 1408)      transpose_task(task, a, smem);
        else if (task < 1664) qcast_task(task - 1408, a);
        else                  emb_task(task - 1664, a);
    }
    gbar(a.bars + 0, NBLK);

    // P1: g1 (emb@W1, silu, 256 tiles 128x64) + qkv (query@Wqkv, 768 tiles)
    for (int rep = 0; rep < 2; ++rep) {
        int id = blk + rep * NBLK;
        if (id < 256)
            gemm_tile<128, 64>(a.embB, a.W1t, a.b1, nullptr, a.hiddenB,
                               512, 256, 1, 0, 8, id, smem);
        else
            gemm_tile<128, 64>(a.queryB, a.Wqkvt, a.biasC, nullptr, a.qkvB,
                               1536, 512, 0, 0, 24, id - 256, smem);
    }
    gbar(a.bars + 32, NBLK);

    // P2: g2 (hidden@W2 -> pe, 512 tiles 64x64, one per block)
    gemm_tile<64, 64>(a.hiddenB, a.W2t, a.b2, nullptr, a.peB,
                      512, 512, 0, 0, 8, blk, smem);
    gbar(a.bars + 64, NBLK);

    // P3: attention (1024 units, 2 per block)
    for (int rep = 0; rep < 2; ++rep) {
        int u = blk + rep * NBLK;
        attn_unit(a.qkvB, a.peB, a.xB, u & 7, (u >> 3) & 63, u >> 9, smem);
    }
    gbar(a.bars + 96, NBLK);

    // P4: out (x@Wo + bo + query, 512 tiles 64x64)
    gemm_tile<64, 64>(a.xB, a.Wot, a.bo, a.query, a.out,
                      512, 512, 0, 1, 8, blk, smem);
}

// ---------------------------------------------------------------------------
extern "C" void kernel_launch(void* const* d_in, const int* in_sizes, int n_in,
                              void* d_out, int out_size, void* d_ws, size_t ws_size,
                              hipStream_t stream) {
    char* ws = (char*)d_ws;

    FusedArgs fa;
    fa.query = (const float*)d_in[0];
    fa.qpos  = (const float*)d_in[1];
    fa.Wq    = (const float*)d_in[2];
    fa.bq    = (const float*)d_in[3];
    fa.Wk    = (const float*)d_in[4];
    fa.Wv    = (const float*)d_in[5];
    fa.bv    = (const float*)d_in[6];
    fa.Wo    = (const float*)d_in[7];
    fa.bo    = (const float*)d_in[8];
    fa.W1    = (const float*)d_in[9];
    fa.b1    = (const float*)d_in[10];
    fa.W2    = (const float*)d_in[11];
    fa.b2    = (const float*)d_in[12];
    fa.out   = (float*)d_out;

    fa.W1t    = (ushort*)(ws + 0);          // [512][256]  256 KB
    fa.W2t    = (ushort*)(ws + 262144);     // [512][512]  512 KB
    fa.Wqkvt  = (ushort*)(ws + 786432);     // [1536][512] 1.5 MB
    fa.Wot    = (ushort*)(ws + 2359296);    // [512][512]  512 KB
    fa.biasC  = (float*) (ws + 2883584);    // [1536]
    fa.embB   = (ushort*)(ws + 3145728);    // [4096][256] 2 MB
    fa.queryB = (ushort*)(ws + 5242880);    // [4096][512] 4 MB
    fa.hiddenB= (ushort*)(ws + 9437184);    // 4 MB
    fa.peB    = (ushort*)(ws + 13631488);   // 4 MB
    fa.qkvB   = (ushort*)(ws + 17825792);   // [4096][1536] 12 MB
    fa.xB     = (ushort*)(ws + 30408704);   // 4 MB -> end 34603008
    fa.bars   = (uint*)  (ws + 34603008);   // 4 x 128 B barrier counters

    hipMemsetAsync(fa.bars, 0, 512, stream);
    fused_all<<<NBLK, 256, 0, stream>>>(fa);
}

// Round 5
// 162.448 us; speedup vs baseline: 3.8613x; 3.8613x over previous
//
#include <hip/hip_runtime.h>
#include <hip/hip_bf16.h>
#include <math.h>

typedef short short8 __attribute__((ext_vector_type(8)));
typedef float floatx4 __attribute__((ext_vector_type(4)));

__device__ __forceinline__ ushort f2bf(float f) {
    __hip_bfloat16 h = __float2bfloat16(f);
    return *reinterpret_cast<ushort*>(&h);
}
__device__ __forceinline__ void bf8_to_f32(uint4 u, float* f) {
    f[0] = __uint_as_float(u.x << 16); f[1] = __uint_as_float(u.x & 0xffff0000u);
    f[2] = __uint_as_float(u.y << 16); f[3] = __uint_as_float(u.y & 0xffff0000u);
    f[4] = __uint_as_float(u.z << 16); f[5] = __uint_as_float(u.z & 0xffff0000u);
    f[6] = __uint_as_float(u.w << 16); f[7] = __uint_as_float(u.w & 0xffff0000u);
}

#define GLDS16(g, l) __builtin_amdgcn_global_load_lds( \
    (const __attribute__((address_space(1))) void*)(g), \
    (__attribute__((address_space(3))) void*)(l), 16, 0, 0)

// ---------------------------------------------------------------------------
// One batched prep kernel. grid (16,16,8), block (32,8). (round-3 exact)
__global__ __launch_bounds__(256) void prep_kernel(
        const float* __restrict__ W1, const float* __restrict__ W2,
        const float* __restrict__ Wq, const float* __restrict__ Wk,
        const float* __restrict__ Wv, const float* __restrict__ Wo,
        const float* __restrict__ bq, const float* __restrict__ bv,
        const float* __restrict__ query, const float* __restrict__ qpos,
        ushort* __restrict__ W1t, ushort* __restrict__ W2t,
        ushort* __restrict__ Wqkvt, ushort* __restrict__ Wot,
        ushort* __restrict__ queryB, ushort* __restrict__ embB,
        float* __restrict__ biasC) {
    const int z = blockIdx.z;
    const int tx = threadIdx.x, ty = threadIdx.y;
    const int tid = ty * 32 + tx;
    if (z < 6) {
        const float* src; ushort* dst; int R;
        switch (z) {
            case 0:  src = W1; dst = W1t;              R = 256; break;
            case 1:  src = W2; dst = W2t;              R = 512; break;
            case 2:  src = Wq; dst = Wqkvt;            R = 512; break;
            case 3:  src = Wk; dst = Wqkvt + 512*512;  R = 512; break;
            case 4:  src = Wv; dst = Wqkvt + 1024*512; R = 512; break;
            default: src = Wo; dst = Wot;              R = 512; break;
        }
        const int r0 = blockIdx.y * 32, c0 = blockIdx.x * 32;
        if (r0 >= R) return;
        __shared__ float t[32][33];
        for (int i = ty; i < 32; i += 8) t[i][tx] = src[(size_t)(r0 + i) * 512 + c0 + tx];
        __syncthreads();
        for (int i = ty; i < 32; i += 8) dst[(size_t)(c0 + i) * R + r0 + tx] = f2bf(t[tx][i]);
    } else if (z == 6) {
        const int bid = blockIdx.y * 16 + blockIdx.x;
#pragma unroll
        for (int i = 0; i < 8; ++i) {
            size_t idx4 = (size_t)bid * 2048 + i * 256 + tid;  // 524288 float4 total
            float4 v = *(const float4*)(query + idx4 * 4);
            ushort4 o; o.x = f2bf(v.x); o.y = f2bf(v.y); o.z = f2bf(v.z); o.w = f2bf(v.w);
            *(ushort4*)(queryB + idx4 * 4) = o;
        }
        if (bid == 0) {
            for (int i = tid; i < 1536; i += 256)
                biasC[i] = (i < 512) ? bq[i] : ((i < 1024) ? 0.0f : bv[i - 1024]);
        }
    } else {
        const int bid = blockIdx.y * 16 + blockIdx.x;
        const int gt = bid * 256 + tid;     // 65536 threads x 16 elems = 1M
        const int e0 = gt * 16;
        const int r = e0 >> 8, j0 = e0 & 255;
        const float t = qpos[r];
        ushort o[16];
#pragma unroll
        for (int u = 0; u < 16; ++u) {
            int j = j0 + u, i = j & 127;
            float freq = __expf(-9.210340371976184f * (float)i * (1.0f / 128.0f));
            float a = t * freq;
            o[u] = f2bf((j < 128) ? __cosf(a) : __sinf(a));
        }
        *(uint4*)(embB + e0)     = *(uint4*)&o[0];
        *(uint4*)(embB + e0 + 8) = *(uint4*)&o[8];
    }
}

// ---------------------------------------------------------------------------
// Multi-problem bf16 MFMA GEMM (round-3 exact): dbuf LDS, one barrier per
// K-step, prefetch issued before compute; two GArgs per launch for TLP.
struct GArgs {
    const ushort* A; const ushort* Bt; const float* bias; const float* resid;
    void* C; int N, K, act, outf32, ntn;   // ntn = N/BN tiles per row
};

template<int BM, int BN>
__global__ __launch_bounds__(256) void gemm_multi(GArgs g0, GArgs g1, int split) {
    constexpr int MR = BM / 32;
    constexpr int NR = BN / 32;
    __shared__ ushort As[2][BM * 32];
    __shared__ ushort Bs[2][BN * 32];

    const bool sel = ((int)blockIdx.x >= split);
    const GArgs g = sel ? g1 : g0;
    const int bid = sel ? ((int)blockIdx.x - split) : (int)blockIdx.x;
    const int tm = bid / g.ntn, tn = bid % g.ntn;
    const int row0 = tm * BM, col0 = tn * BN;
    const int K = g.K, N = g.N;

    const int tid = threadIdx.x;
    const int l = tid & 63, w = tid >> 6;
    const int wr = w >> 1, wc = w & 1;
    const int l15 = l & 15, quad = l >> 4;

    const int srow = tid >> 2;
    const int skoff = (tid & 3) * 8;
    const ushort* gA = g.A  + (size_t)(row0 + srow) * K + skoff;
    const ushort* gB = g.Bt + (size_t)(col0 + srow) * K + skoff;

    auto stage = [&](int s, int k0) {
#pragma unroll
        for (int i = 0; i < BM / 64; ++i)
            GLDS16(gA + (size_t)(i * 64) * K + k0, &As[s][(i * 256 + tid) * 8]);
#pragma unroll
        for (int i = 0; i < BN / 64; ++i)
            GLDS16(gB + (size_t)(i * 64) * K + k0, &Bs[s][(i * 256 + tid) * 8]);
    };

    floatx4 acc[MR][NR] = {};

    const int nk = K >> 5;
    stage(0, 0);
    int cur = 0;
    for (int t = 0; t < nk; ++t) {
        __syncthreads();        // drains vmcnt(0): stage(t) visible
        if (t + 1 < nk) stage(cur ^ 1, (t + 1) * 32);   // prefetch early
        short8 af[MR], bf[NR];
#pragma unroll
        for (int m = 0; m < MR; ++m)
            af[m] = *(const short8*)&As[cur][(wr * (BM / 2) + m * 16 + l15) * 32 + quad * 8];
#pragma unroll
        for (int n = 0; n < NR; ++n)
            bf[n] = *(const short8*)&Bs[cur][(wc * (BN / 2) + n * 16 + l15) * 32 + quad * 8];
#pragma unroll
        for (int m = 0; m < MR; ++m)
#pragma unroll
            for (int n = 0; n < NR; ++n)
                acc[m][n] = __builtin_amdgcn_mfma_f32_16x16x32_bf16(af[m], bf[n], acc[m][n], 0, 0, 0);
        cur ^= 1;
    }

#pragma unroll
    for (int m = 0; m < MR; ++m)
#pragma unroll
        for (int n = 0; n < NR; ++n) {
            int col = col0 + wc * (BN / 2) + n * 16 + l15;
            float bvv = g.bias ? g.bias[col] : 0.0f;
#pragma unroll
            for (int r = 0; r < 4; ++r) {
                int row = row0 + wr * (BM / 2) + m * 16 + quad * 4 + r;
                float val = acc[m][n][r] + bvv;
                if (g.act) val = val / (1.0f + __expf(-val));
                if (g.outf32) {
                    float rv = g.resid ? g.resid[(size_t)row * N + col] : 0.0f;
                    ((float*)g.C)[(size_t)row * N + col] = val + rv;
                } else {
                    ((ushort*)g.C)[(size_t)row * N + col] = f2bf(val);
                }
            }
        }
}

// ---------------------------------------------------------------------------
// Attention v2. Block = 256 thr per (h, b, nhalf) = 32 q-rows x 64 keys x 64d.
// Changes vs v1:
//  - ks/vs rows padded to 68 f32: b128 read start-bank = (4*hi + 8*lo) mod 32
//    spreads over all 32 banks -> 8-cycle floor (was 16-bank / 2x penalty).
//  - PV restructured: softmax'd probs go to LDS p[32][66] (bf16), one sync,
//    then thread (n, d-chunk) owns its output: 64 broadcast p-reads +
//    conflict-free vs reads, ZERO cross-lane shuffles (was 24 bpermute/iter).
//  - q read straight from global (each row used once; qs staging dropped),
//    pe loads for all 8 m-groups batched up front.
// LDS: 2*64*68*4 + 32*66*2 = 39040 B -> 4 blocks/CU kept.
__global__ __launch_bounds__(256) void attn_bf16(
        const ushort* __restrict__ qkv, const ushort* __restrict__ peB,
        ushort* __restrict__ xB) {
    constexpr int LP = 68;   // f32 row stride for ks/vs
    constexpr int PP = 66;   // ushort row stride for p
    const int h = blockIdx.x, b = blockIdx.y, nh = blockIdx.z;
    const int tid = threadIdx.x;
    const int w = tid >> 6, l = tid & 63;
    const int lo = l & 7, hi = l >> 3;

    __shared__ float ks[64 * LP];
    __shared__ float vs[64 * LP];
    __shared__ ushort ps[32 * PP];

    // stage K and V (f32, padded rows)
#pragma unroll
    for (int p = 0; p < 2; ++p) {
        int cid = p * 256 + tid;
        int row = cid >> 3, ch = cid & 7;
        const ushort* base = qkv + (size_t)(b * 64 + row) * 1536 + h * 64 + ch * 8;
        uint4 ku = *(const uint4*)(base + 512);
        uint4 vu = *(const uint4*)(base + 1024);
        float kf[8], vf[8];
        bf8_to_f32(ku, kf); bf8_to_f32(vu, vf);
#pragma unroll
        for (int j = 0; j < 8; ++j) {
            ks[row * LP + ch * 8 + j] = kf[j];
            vs[row * LP + ch * 8 + j] = vf[j];
        }
    }
    __syncthreads();

    // Phase A: scores + softmax; probabilities to LDS (bf16)
    for (int i = 0; i < 8; ++i) {
        int nl = w + 4 * i;
        int n = nh * 32 + nl;

        // q direct from global (one row per (wave,i), d-chunk lo)
        uint4 qu = *(const uint4*)(qkv + (size_t)(b * 64 + n) * 1536 + h * 64 + lo * 8);
        float qf[8]; bf8_to_f32(qu, qf);

        // batch all 8 pe loads
        uint4 pu[8];
#pragma unroll
        for (int mg = 0; mg < 8; ++mg)
            pu[mg] = *(const uint4*)(peB + (size_t)(n * 64 + mg * 8 + hi) * 512 + h * 64 + lo * 8);

        float sreg[8];
#pragma unroll
        for (int mg = 0; mg < 8; ++mg) {
            int m = mg * 8 + hi;
            float pf[8]; bf8_to_f32(pu[mg], pf);
            float kf[8];
            *(float4*)&kf[0] = *(const float4*)&ks[m * LP + lo * 8];
            *(float4*)&kf[4] = *(const float4*)&ks[m * LP + lo * 8 + 4];
            float p = 0.0f;
#pragma unroll
            for (int j = 0; j < 8; ++j) p = fmaf(qf[j] * kf[j], pf[j], p);
            p += __shfl_xor(p, 1);
            p += __shfl_xor(p, 2);
            p += __shfl_xor(p, 4);
            sreg[mg] = p * 0.125f;
        }

        float mx = sreg[0];
#pragma unroll
        for (int mg = 1; mg < 8; ++mg) mx = fmaxf(mx, sreg[mg]);
        mx = fmaxf(mx, __shfl_xor(mx, 8));
        mx = fmaxf(mx, __shfl_xor(mx, 16));
        mx = fmaxf(mx, __shfl_xor(mx, 32));
        float sum = 0.0f;
#pragma unroll
        for (int mg = 0; mg < 8; ++mg) { sreg[mg] = __expf(sreg[mg] - mx); sum += sreg[mg]; }
        sum += __shfl_xor(sum, 8);
        sum += __shfl_xor(sum, 16);
        sum += __shfl_xor(sum, 32);
        float rs = 1.0f / sum;

        // lane (hi,lo) writes prob for m = 8*lo + hi (its sreg[lo]) -> p row full
        float pv = sreg[0];
#pragma unroll
        for (int mg = 1; mg < 8; ++mg) if (lo == mg) pv = sreg[mg];
        ps[nl * PP + 8 * lo + hi] = f2bf(pv * rs);
    }
    __syncthreads();

    // Phase B: PV. thread = (n8, dch); no cross-lane reduction.
    {
        const int n8 = tid >> 3, dch = tid & 7;
        float acc[8] = {};
#pragma unroll 4
        for (int m = 0; m < 64; ++m) {
            float at = __uint_as_float(((uint)ps[n8 * PP + m]) << 16);
            float vf[8];
            *(float4*)&vf[0] = *(const float4*)&vs[m * LP + dch * 8];
            *(float4*)&vf[4] = *(const float4*)&vs[m * LP + dch * 8 + 4];
#pragma unroll
            for (int j = 0; j < 8; ++j) acc[j] = fmaf(at, vf[j], acc[j]);
        }
        int n = nh * 32 + n8;
        uint4 o;
        o.x = f2bf(acc[0]) | ((uint)f2bf(acc[1]) << 16);
        o.y = f2bf(acc[2]) | ((uint)f2bf(acc[3]) << 16);
        o.z = f2bf(acc[4]) | ((uint)f2bf(acc[5]) << 16);
        o.w = f2bf(acc[6]) | ((uint)f2bf(acc[7]) << 16);
        *(uint4*)(xB + (size_t)(b * 64 + n) * 512 + h * 64 + dch * 8) = o;
    }
}

// ---------------------------------------------------------------------------
extern "C" void kernel_launch(void* const* d_in, const int* in_sizes, int n_in,
                              void* d_out, int out_size, void* d_ws, size_t ws_size,
                              hipStream_t stream) {
    const float* query = (const float*)d_in[0];
    const float* qpos  = (const float*)d_in[1];
    const float* Wq    = (const float*)d_in[2];
    const float* bq    = (const float*)d_in[3];
    const float* Wk    = (const float*)d_in[4];
    const float* Wv    = (const float*)d_in[5];
    const float* bv    = (const float*)d_in[6];
    const float* Wo    = (const float*)d_in[7];
    const float* bo    = (const float*)d_in[8];
    const float* W1    = (const float*)d_in[9];
    const float* b1    = (const float*)d_in[10];
    const float* W2    = (const float*)d_in[11];
    const float* b2    = (const float*)d_in[12];
    float* out = (float*)d_out;
    char* ws = (char*)d_ws;

    ushort* W1t    = (ushort*)(ws + 0);          // [512][256]  256 KB
    ushort* W2t    = (ushort*)(ws + 262144);     // [512][512]  512 KB
    ushort* Wqkvt  = (ushort*)(ws + 786432);     // [1536][512] 1.5 MB
    ushort* Wot    = (ushort*)(ws + 2359296);    // [512][512]  512 KB
    float*  biasC  = (float*) (ws + 2883584);    // [1536]
    ushort* embB   = (ushort*)(ws + 3145728);    // [4096][256] 2 MB
    ushort* queryB = (ushort*)(ws + 5242880);    // [4096][512] 4 MB
    ushort* hiddenB= (ushort*)(ws + 9437184);    // 4 MB
    ushort* peB    = (ushort*)(ws + 13631488);   // 4 MB
    ushort* qkvB   = (ushort*)(ws + 17825792);   // [4096][1536] 12 MB
    ushort* xB     = (ushort*)(ws + 30408704);   // 4 MB -> end 34.6 MB

    prep_kernel<<<dim3(16, 16, 8), dim3(32, 8), 0, stream>>>(
        W1, W2, Wq, Wk, Wv, Wo, bq, bv, query, qpos,
        W1t, W2t, Wqkvt, Wot, queryB, embB, biasC);

    GArgs a_g1 { embB,    W1t,   b1,    nullptr, hiddenB, 512,  256, 1, 0, 8  };
    GArgs a_g2 { hiddenB, W2t,   b2,    nullptr, peB,     512,  512, 0, 0, 8  };
    GArgs a_qkv{ queryB,  Wqkvt, biasC, nullptr, qkvB,    1536, 512, 0, 0, 24 };
    GArgs a_out{ xB,      Wot,   bo,    query,   out,     512,  512, 0, 1, 8  };

    // g1: emb @ W1 (silu). 256 blocks.
    gemm_multi<128, 64><<<256, 256, 0, stream>>>(a_g1, a_g1, 1 << 30);
    // fused: [hidden @ W2 -> pe] + [query @ Wqkv -> qkv] (independent), 1024 blocks.
    gemm_multi<128, 64><<<1024, 256, 0, stream>>>(a_g2, a_qkv, 256);

    attn_bf16<<<dim3(8, 64, 2), 256, 0, stream>>>(qkvB, peB, xB);

    // out: x @ Wo + bo + query. 256 blocks.
    gemm_multi<128, 64><<<256, 256, 0, stream>>>(a_out, a_out, 1 << 30);
}

// Round 6
// 157.492 us; speedup vs baseline: 3.9828x; 1.0315x over previous
//
#include <hip/hip_runtime.h>
#include <hip/hip_bf16.h>
#include <math.h>

typedef short short8 __attribute__((ext_vector_type(8)));
typedef float floatx4 __attribute__((ext_vector_type(4)));

__device__ __forceinline__ ushort f2bf(float f) {
    __hip_bfloat16 h = __float2bfloat16(f);
    return *reinterpret_cast<ushort*>(&h);
}
__device__ __forceinline__ void bf8_to_f32(uint4 u, float* f) {
    f[0] = __uint_as_float(u.x << 16); f[1] = __uint_as_float(u.x & 0xffff0000u);
    f[2] = __uint_as_float(u.y << 16); f[3] = __uint_as_float(u.y & 0xffff0000u);
    f[4] = __uint_as_float(u.z << 16); f[5] = __uint_as_float(u.z & 0xffff0000u);
    f[6] = __uint_as_float(u.w << 16); f[7] = __uint_as_float(u.w & 0xffff0000u);
}

#define GLDS16(g, l) __builtin_amdgcn_global_load_lds( \
    (const __attribute__((address_space(1))) void*)(g), \
    (__attribute__((address_space(3))) void*)(l), 16, 0, 0)

// ---------------------------------------------------------------------------
// One batched prep kernel. grid (16,16,8), block (32,8). (unchanged)
__global__ __launch_bounds__(256) void prep_kernel(
        const float* __restrict__ W1, const float* __restrict__ W2,
        const float* __restrict__ Wq, const float* __restrict__ Wk,
        const float* __restrict__ Wv, const float* __restrict__ Wo,
        const float* __restrict__ bq, const float* __restrict__ bv,
        const float* __restrict__ query, const float* __restrict__ qpos,
        ushort* __restrict__ W1t, ushort* __restrict__ W2t,
        ushort* __restrict__ Wqkvt, ushort* __restrict__ Wot,
        ushort* __restrict__ queryB, ushort* __restrict__ embB,
        float* __restrict__ biasC) {
    const int z = blockIdx.z;
    const int tx = threadIdx.x, ty = threadIdx.y;
    const int tid = ty * 32 + tx;
    if (z < 6) {
        const float* src; ushort* dst; int R;
        switch (z) {
            case 0:  src = W1; dst = W1t;              R = 256; break;
            case 1:  src = W2; dst = W2t;              R = 512; break;
            case 2:  src = Wq; dst = Wqkvt;            R = 512; break;
            case 3:  src = Wk; dst = Wqkvt + 512*512;  R = 512; break;
            case 4:  src = Wv; dst = Wqkvt + 1024*512; R = 512; break;
            default: src = Wo; dst = Wot;              R = 512; break;
        }
        const int r0 = blockIdx.y * 32, c0 = blockIdx.x * 32;
        if (r0 >= R) return;
        __shared__ float t[32][33];
        for (int i = ty; i < 32; i += 8) t[i][tx] = src[(size_t)(r0 + i) * 512 + c0 + tx];
        __syncthreads();
        for (int i = ty; i < 32; i += 8) dst[(size_t)(c0 + i) * R + r0 + tx] = f2bf(t[tx][i]);
    } else if (z == 6) {
        const int bid = blockIdx.y * 16 + blockIdx.x;
#pragma unroll
        for (int i = 0; i < 8; ++i) {
            size_t idx4 = (size_t)bid * 2048 + i * 256 + tid;  // 524288 float4 total
            float4 v = *(const float4*)(query + idx4 * 4);
            ushort4 o; o.x = f2bf(v.x); o.y = f2bf(v.y); o.z = f2bf(v.z); o.w = f2bf(v.w);
            *(ushort4*)(queryB + idx4 * 4) = o;
        }
        if (bid == 0) {
            for (int i = tid; i < 1536; i += 256)
                biasC[i] = (i < 512) ? bq[i] : ((i < 1024) ? 0.0f : bv[i - 1024]);
        }
    } else {
        const int bid = blockIdx.y * 16 + blockIdx.x;
        const int gt = bid * 256 + tid;     // 65536 threads x 16 elems = 1M
        const int e0 = gt * 16;
        const int r = e0 >> 8, j0 = e0 & 255;
        const float t = qpos[r];
        ushort o[16];
#pragma unroll
        for (int u = 0; u < 16; ++u) {
            int j = j0 + u, i = j & 127;
            float freq = __expf(-9.210340371976184f * (float)i * (1.0f / 128.0f));
            float a = t * freq;
            o[u] = f2bf((j < 128) ? __cosf(a) : __sinf(a));
        }
        *(uint4*)(embB + e0)     = *(uint4*)&o[0];
        *(uint4*)(embB + e0 + 8) = *(uint4*)&o[8];
    }
}

// ---------------------------------------------------------------------------
// Multi-problem bf16 MFMA GEMM: dbuf LDS, one barrier per K-step, prefetch
// issued before compute (round-3 pipeline). This round: 64x64 tiles
// EVERYWHERE -> 512..2048 blocks per launch (2..8 blocks/CU). Round 0 vs
// round 3 showed TLP and pipelining each buy the same; this combines both.
// LDS 16 KB, ~76 VGPR -> ~6 blocks/CU resident on the big fused launch.
struct GArgs {
    const ushort* A; const ushort* Bt; const float* bias; const float* resid;
    void* C; int N, K, act, outf32, ntn;   // ntn = N/BN tiles per row
};

template<int BM, int BN>
__global__ __launch_bounds__(256) void gemm_multi(GArgs g0, GArgs g1, int split) {
    constexpr int MR = BM / 32;
    constexpr int NR = BN / 32;
    __shared__ ushort As[2][BM * 32];
    __shared__ ushort Bs[2][BN * 32];

    const bool sel = ((int)blockIdx.x >= split);
    const GArgs g = sel ? g1 : g0;
    const int bid = sel ? ((int)blockIdx.x - split) : (int)blockIdx.x;
    const int tm = bid / g.ntn, tn = bid % g.ntn;
    const int row0 = tm * BM, col0 = tn * BN;
    const int K = g.K, N = g.N;

    const int tid = threadIdx.x;
    const int l = tid & 63, w = tid >> 6;
    const int wr = w >> 1, wc = w & 1;
    const int l15 = l & 15, quad = l >> 4;

    const int srow = tid >> 2;
    const int skoff = (tid & 3) * 8;
    const ushort* gA = g.A  + (size_t)(row0 + srow) * K + skoff;
    const ushort* gB = g.Bt + (size_t)(col0 + srow) * K + skoff;

    auto stage = [&](int s, int k0) {
#pragma unroll
        for (int i = 0; i < BM / 64; ++i)
            GLDS16(gA + (size_t)(i * 64) * K + k0, &As[s][(i * 256 + tid) * 8]);
#pragma unroll
        for (int i = 0; i < BN / 64; ++i)
            GLDS16(gB + (size_t)(i * 64) * K + k0, &Bs[s][(i * 256 + tid) * 8]);
    };

    floatx4 acc[MR][NR] = {};

    const int nk = K >> 5;
    stage(0, 0);
    int cur = 0;
    for (int t = 0; t < nk; ++t) {
        __syncthreads();        // drains vmcnt(0): stage(t) visible
        if (t + 1 < nk) stage(cur ^ 1, (t + 1) * 32);   // prefetch early
        short8 af[MR], bf[NR];
#pragma unroll
        for (int m = 0; m < MR; ++m)
            af[m] = *(const short8*)&As[cur][(wr * (BM / 2) + m * 16 + l15) * 32 + quad * 8];
#pragma unroll
        for (int n = 0; n < NR; ++n)
            bf[n] = *(const short8*)&Bs[cur][(wc * (BN / 2) + n * 16 + l15) * 32 + quad * 8];
#pragma unroll
        for (int m = 0; m < MR; ++m)
#pragma unroll
            for (int n = 0; n < NR; ++n)
                acc[m][n] = __builtin_amdgcn_mfma_f32_16x16x32_bf16(af[m], bf[n], acc[m][n], 0, 0, 0);
        cur ^= 1;
    }

#pragma unroll
    for (int m = 0; m < MR; ++m)
#pragma unroll
        for (int n = 0; n < NR; ++n) {
            int col = col0 + wc * (BN / 2) + n * 16 + l15;
            float bvv = g.bias ? g.bias[col] : 0.0f;
#pragma unroll
            for (int r = 0; r < 4; ++r) {
                int row = row0 + wr * (BM / 2) + m * 16 + quad * 4 + r;
                float val = acc[m][n][r] + bvv;
                if (g.act) val = val / (1.0f + __expf(-val));
                if (g.outf32) {
                    float rv = g.resid ? g.resid[(size_t)row * N + col] : 0.0f;
                    ((float*)g.C)[(size_t)row * N + col] = val + rv;
                } else {
                    ((ushort*)g.C)[(size_t)row * N + col] = f2bf(val);
                }
            }
        }
}

// ---------------------------------------------------------------------------
// Attention v2 (round-5 exact, unchanged for attribution).
__global__ __launch_bounds__(256) void attn_bf16(
        const ushort* __restrict__ qkv, const ushort* __restrict__ peB,
        ushort* __restrict__ xB) {
    constexpr int LP = 68;   // f32 row stride for ks/vs
    constexpr int PP = 66;   // ushort row stride for p
    const int h = blockIdx.x, b = blockIdx.y, nh = blockIdx.z;
    const int tid = threadIdx.x;
    const int w = tid >> 6, l = tid & 63;
    const int lo = l & 7, hi = l >> 3;

    __shared__ float ks[64 * LP];
    __shared__ float vs[64 * LP];
    __shared__ ushort ps[32 * PP];

#pragma unroll
    for (int p = 0; p < 2; ++p) {
        int cid = p * 256 + tid;
        int row = cid >> 3, ch = cid & 7;
        const ushort* base = qkv + (size_t)(b * 64 + row) * 1536 + h * 64 + ch * 8;
        uint4 ku = *(const uint4*)(base + 512);
        uint4 vu = *(const uint4*)(base + 1024);
        float kf[8], vf[8];
        bf8_to_f32(ku, kf); bf8_to_f32(vu, vf);
#pragma unroll
        for (int j = 0; j < 8; ++j) {
            ks[row * LP + ch * 8 + j] = kf[j];
            vs[row * LP + ch * 8 + j] = vf[j];
        }
    }
    __syncthreads();

    // Phase A: scores + softmax; probabilities to LDS (bf16)
    for (int i = 0; i < 8; ++i) {
        int nl = w + 4 * i;
        int n = nh * 32 + nl;

        uint4 qu = *(const uint4*)(qkv + (size_t)(b * 64 + n) * 1536 + h * 64 + lo * 8);
        float qf[8]; bf8_to_f32(qu, qf);

        uint4 pu[8];
#pragma unroll
        for (int mg = 0; mg < 8; ++mg)
            pu[mg] = *(const uint4*)(peB + (size_t)(n * 64 + mg * 8 + hi) * 512 + h * 64 + lo * 8);

        float sreg[8];
#pragma unroll
        for (int mg = 0; mg < 8; ++mg) {
            int m = mg * 8 + hi;
            float pf[8]; bf8_to_f32(pu[mg], pf);
            float kf[8];
            *(float4*)&kf[0] = *(const float4*)&ks[m * LP + lo * 8];
            *(float4*)&kf[4] = *(const float4*)&ks[m * LP + lo * 8 + 4];
            float p = 0.0f;
#pragma unroll
            for (int j = 0; j < 8; ++j) p = fmaf(qf[j] * kf[j], pf[j], p);
            p += __shfl_xor(p, 1);
            p += __shfl_xor(p, 2);
            p += __shfl_xor(p, 4);
            sreg[mg] = p * 0.125f;
        }

        float mx = sreg[0];
#pragma unroll
        for (int mg = 1; mg < 8; ++mg) mx = fmaxf(mx, sreg[mg]);
        mx = fmaxf(mx, __shfl_xor(mx, 8));
        mx = fmaxf(mx, __shfl_xor(mx, 16));
        mx = fmaxf(mx, __shfl_xor(mx, 32));
        float sum = 0.0f;
#pragma unroll
        for (int mg = 0; mg < 8; ++mg) { sreg[mg] = __expf(sreg[mg] - mx); sum += sreg[mg]; }
        sum += __shfl_xor(sum, 8);
        sum += __shfl_xor(sum, 16);
        sum += __shfl_xor(sum, 32);
        float rs = 1.0f / sum;

        float pv = sreg[0];
#pragma unroll
        for (int mg = 1; mg < 8; ++mg) if (lo == mg) pv = sreg[mg];
        ps[nl * PP + 8 * lo + hi] = f2bf(pv * rs);
    }
    __syncthreads();

    // Phase B: PV. thread = (n8, dch); no cross-lane reduction.
    {
        const int n8 = tid >> 3, dch = tid & 7;
        float acc[8] = {};
#pragma unroll 4
        for (int m = 0; m < 64; ++m) {
            float at = __uint_as_float(((uint)ps[n8 * PP + m]) << 16);
            float vf[8];
            *(float4*)&vf[0] = *(const float4*)&vs[m * LP + dch * 8];
            *(float4*)&vf[4] = *(const float4*)&vs[m * LP + dch * 8 + 4];
#pragma unroll
            for (int j = 0; j < 8; ++j) acc[j] = fmaf(at, vf[j], acc[j]);
        }
        int n = nh * 32 + n8;
        uint4 o;
        o.x = f2bf(acc[0]) | ((uint)f2bf(acc[1]) << 16);
        o.y = f2bf(acc[2]) | ((uint)f2bf(acc[3]) << 16);
        o.z = f2bf(acc[4]) | ((uint)f2bf(acc[5]) << 16);
        o.w = f2bf(acc[6]) | ((uint)f2bf(acc[7]) << 16);
        *(uint4*)(xB + (size_t)(b * 64 + n) * 512 + h * 64 + dch * 8) = o;
    }
}

// ---------------------------------------------------------------------------
extern "C" void kernel_launch(void* const* d_in, const int* in_sizes, int n_in,
                              void* d_out, int out_size, void* d_ws, size_t ws_size,
                              hipStream_t stream) {
    const float* query = (const float*)d_in[0];
    const float* qpos  = (const float*)d_in[1];
    const float* Wq    = (const float*)d_in[2];
    const float* bq    = (const float*)d_in[3];
    const float* Wk    = (const float*)d_in[4];
    const float* Wv    = (const float*)d_in[5];
    const float* bv    = (const float*)d_in[6];
    const float* Wo    = (const float*)d_in[7];
    const float* bo    = (const float*)d_in[8];
    const float* W1    = (const float*)d_in[9];
    const float* b1    = (const float*)d_in[10];
    const float* W2    = (const float*)d_in[11];
    const float* b2    = (const float*)d_in[12];
    float* out = (float*)d_out;
    char* ws = (char*)d_ws;

    ushort* W1t    = (ushort*)(ws + 0);          // [512][256]  256 KB
    ushort* W2t    = (ushort*)(ws + 262144);     // [512][512]  512 KB
    ushort* Wqkvt  = (ushort*)(ws + 786432);     // [1536][512] 1.5 MB
    ushort* Wot    = (ushort*)(ws + 2359296);    // [512][512]  512 KB
    float*  biasC  = (float*) (ws + 2883584);    // [1536]
    ushort* embB   = (ushort*)(ws + 3145728);    // [4096][256] 2 MB
    ushort* queryB = (ushort*)(ws + 5242880);    // [4096][512] 4 MB
    ushort* hiddenB= (ushort*)(ws + 9437184);    // 4 MB
    ushort* peB    = (ushort*)(ws + 13631488);   // 4 MB
    ushort* qkvB   = (ushort*)(ws + 17825792);   // [4096][1536] 12 MB
    ushort* xB     = (ushort*)(ws + 30408704);   // 4 MB -> end 34.6 MB

    prep_kernel<<<dim3(16, 16, 8), dim3(32, 8), 0, stream>>>(
        W1, W2, Wq, Wk, Wv, Wo, bq, bv, query, qpos,
        W1t, W2t, Wqkvt, Wot, queryB, embB, biasC);

    GArgs a_g1 { embB,    W1t,   b1,    nullptr, hiddenB, 512,  256, 1, 0, 8  };
    GArgs a_g2 { hiddenB, W2t,   b2,    nullptr, peB,     512,  512, 0, 0, 8  };
    GArgs a_qkv{ queryB,  Wqkvt, biasC, nullptr, qkvB,    1536, 512, 0, 0, 24 };
    GArgs a_out{ xB,      Wot,   bo,    query,   out,     512,  512, 0, 1, 8  };

    // g1: emb @ W1 (silu). 512 tiles of 64x64 -> 2 blocks/CU.
    gemm_multi<64, 64><<<512, 256, 0, stream>>>(a_g1, a_g1, 1 << 30);
    // fused: [hidden @ W2 -> pe, 512 tiles] + [query @ Wqkv -> qkv, 1536 tiles]
    // = 2048 blocks -> up to 8 blocks/CU (VGPR allows ~6): round-0 TLP with
    // the round-3 prefetch pipeline.
    gemm_multi<64, 64><<<2048, 256, 0, stream>>>(a_g2, a_qkv, 512);

    attn_bf16<<<dim3(8, 64, 2), 256, 0, stream>>>(qkvB, peB, xB);

    // out: x @ Wo + bo + query. 512 tiles.
    gemm_multi<64, 64><<<512, 256, 0, stream>>>(a_out, a_out, 1 << 30);
}